// Round 1
// baseline (383.952 us; speedup 1.0000x reference)
//
#include <hip/hip_runtime.h>

// CARAFE-style SAU: enc conv3x3+BN+ReLU -> kernel/gate predictors -> softmax(100)
// -> 5x5 content-aware reassembly, pixel shuffle x2.
// N=8, Cin=128, H=W=64, Cmid=64, NK=100, K=5, S=2. All fp32 (round 0: correctness).

#define HW64 64

// ---------------- conv3x3 (+BN+ReLU or +bias+ReLU) ----------------
// x: (N, CIN, 64, 64), wt: (64, CIN, 3, 3), out: (N, 64, 64, 64)
// One block per (n, h): computes all 64 cout x 64 w of one row.
// Thread tile: 4 w x 4 co. LDS stages 16-ci chunk of x rows + weights.
template<int CIN, bool BN>
__global__ __launch_bounds__(256) void conv3x3_k(
    const float* __restrict__ x, const float* __restrict__ wt,
    const float* __restrict__ bias, const float* __restrict__ gamma,
    const float* __restrict__ beta, const float* __restrict__ mean,
    const float* __restrict__ var, float* __restrict__ out)
{
    constexpr int CI_T = 16;
    __shared__ float xs[CI_T][3][68];     // [ci][kh][col] col = w+1 (zero pad), pad 68 for b128 align
    __shared__ float ws[CI_T * 9][64];    // [ci*9+kh*3+kw][co]
    const int blk = blockIdx.x;
    const int n = blk >> 6, h = blk & 63;
    const int tid = threadIdx.x;
    const int wg = tid & 15, cg = tid >> 4;
    const int w0 = wg * 4, co0 = cg * 4;
    float acc[4][4] = {};

    for (int ci0 = 0; ci0 < CIN; ci0 += CI_T) {
        __syncthreads();
        // stage x rows h-1..h+1, cols -1..64 (zero pad)
        for (int idx = tid; idx < CI_T * 3 * 66; idx += 256) {
            int ci = idx / 198, r = idx % 198;
            int kh = r / 66, col = r % 66;
            int hh = h + kh - 1, wc = col - 1;
            float v = 0.f;
            if ((unsigned)hh < 64u && (unsigned)wc < 64u)
                v = x[((n * CIN + ci0 + ci) * 64 + hh) * 64 + wc];
            xs[ci][kh][col] = v;
        }
        // stage weights: global (co, ci, 3, 3) -> ws[r][co]
        for (int idx = tid; idx < 64 * CI_T * 9; idx += 256) {
            int co = idx / (CI_T * 9), r = idx % (CI_T * 9);
            ws[r][co] = wt[(co * CIN + ci0) * 9 + r];
        }
        __syncthreads();
        for (int ci = 0; ci < CI_T; ++ci) {
            #pragma unroll
            for (int kh = 0; kh < 3; ++kh) {
                float xv[6];
                #pragma unroll
                for (int d = 0; d < 6; ++d) xv[d] = xs[ci][kh][w0 + d];
                #pragma unroll
                for (int kw = 0; kw < 3; ++kw) {
                    const float4 wv = *(const float4*)&ws[ci * 9 + kh * 3 + kw][co0];
                    #pragma unroll
                    for (int a = 0; a < 4; ++a) {
                        acc[a][0] = fmaf(xv[a + kw], wv.x, acc[a][0]);
                        acc[a][1] = fmaf(xv[a + kw], wv.y, acc[a][1]);
                        acc[a][2] = fmaf(xv[a + kw], wv.z, acc[a][2]);
                        acc[a][3] = fmaf(xv[a + kw], wv.w, acc[a][3]);
                    }
                }
            }
        }
    }
    #pragma unroll
    for (int b = 0; b < 4; ++b) {
        const int c = co0 + b;
        float sc, sh;
        if constexpr (BN) {
            float inv = rsqrtf(var[c] + 1e-5f);
            sc = gamma[c] * inv;
            sh = (bias[c] - mean[c]) * sc + beta[c];
        } else {
            sc = 1.f; sh = bias[c];
        }
        float4 o;
        o.x = fmaxf(fmaf(acc[0][b], sc, sh), 0.f);
        o.y = fmaxf(fmaf(acc[1][b], sc, sh), 0.f);
        o.z = fmaxf(fmaf(acc[2][b], sc, sh), 0.f);
        o.w = fmaxf(fmaf(acc[3][b], sc, sh), 0.f);
        *(float4*)&out[((n * 64 + c) * 64 + h) * 64 + w0] = o;
    }
}

// ---------------- fused kernel/gate predictor + softmax ----------------
// content,g1: (N,64,64,64); wkp,wg2: (100,64); out ker: (N,H,W,100) pixel-major.
// One block per (n,h) row. tid = w + 64*qg; each thread owns 25 of the 100 q.
__global__ __launch_bounds__(256) void predictor_k(
    const float* __restrict__ content, const float* __restrict__ g1,
    const float* __restrict__ wkp, const float* __restrict__ bkp,
    const float* __restrict__ wg2, const float* __restrict__ bg2,
    float* __restrict__ ker)
{
    __shared__ float cs[64 * 68];    // [w][ci], pad 68
    __shared__ float gs[64 * 68];
    __shared__ float wsm[100 * 64];  // [q][ci] (staged twice: wkp then wg2)
    __shared__ float redm[256], reds[256];
    const int blk = blockIdx.x;
    const int n = blk >> 6, h = blk & 63;
    const int tid = threadIdx.x;
    const int w = tid & 63, qg = tid >> 6;

    // stage content & g1 rows, transposed to [w][ci]
    for (int idx = tid; idx < 64 * 64; idx += 256) {
        int ci = idx >> 6, ww = idx & 63;
        const int gidx = ((n * 64 + ci) * 64 + h) * 64 + ww;
        cs[ww * 68 + ci] = content[gidx];
        gs[ww * 68 + ci] = g1[gidx];
    }
    for (int idx = tid; idx < 6400; idx += 256) wsm[idx] = wkp[idx];
    __syncthreads();

    float ka[25], ga[25];
    #pragma unroll
    for (int j = 0; j < 25; ++j) ka[j] = bkp[qg * 25 + j];
    for (int ci = 0; ci < 64; ci += 4) {
        const float4 cv = *(const float4*)&cs[w * 68 + ci];
        #pragma unroll
        for (int j = 0; j < 25; ++j) {
            const float4 wv = *(const float4*)&wsm[(qg * 25 + j) * 64 + ci];
            ka[j] = fmaf(cv.x, wv.x, ka[j]);
            ka[j] = fmaf(cv.y, wv.y, ka[j]);
            ka[j] = fmaf(cv.z, wv.z, ka[j]);
            ka[j] = fmaf(cv.w, wv.w, ka[j]);
        }
    }
    __syncthreads();
    for (int idx = tid; idx < 6400; idx += 256) wsm[idx] = wg2[idx];
    __syncthreads();
    #pragma unroll
    for (int j = 0; j < 25; ++j) ga[j] = bg2[qg * 25 + j];
    for (int ci = 0; ci < 64; ci += 4) {
        const float4 gv = *(const float4*)&gs[w * 68 + ci];
        #pragma unroll
        for (int j = 0; j < 25; ++j) {
            const float4 wv = *(const float4*)&wsm[(qg * 25 + j) * 64 + ci];
            ga[j] = fmaf(gv.x, wv.x, ga[j]);
            ga[j] = fmaf(gv.y, wv.y, ga[j]);
            ga[j] = fmaf(gv.z, wv.z, ga[j]);
            ga[j] = fmaf(gv.w, wv.w, ga[j]);
        }
    }

    // p = kernel * sigmoid(gate); softmax over 100 (4 threads x 25)
    float p[25], m = -1e30f;
    #pragma unroll
    for (int j = 0; j < 25; ++j) {
        float s = 1.f / (1.f + __expf(-ga[j]));
        p[j] = ka[j] * s;
        m = fmaxf(m, p[j]);
    }
    redm[tid] = m;
    __syncthreads();
    m = fmaxf(fmaxf(redm[w], redm[64 + w]), fmaxf(redm[128 + w], redm[192 + w]));
    float ssum = 0.f;
    #pragma unroll
    for (int j = 0; j < 25; ++j) { p[j] = __expf(p[j] - m); ssum += p[j]; }
    reds[tid] = ssum;
    __syncthreads();
    ssum = reds[w] + reds[64 + w] + reds[128 + w] + reds[192 + w];
    const float r = 1.f / ssum;

    // normalized values -> LDS (reuse cs region) -> coalesced global store
    float* sm = cs;  // 6400 floats fit in cs(4352)+gs region (contiguous)
    #pragma unroll
    for (int j = 0; j < 25; ++j) sm[w * 100 + qg * 25 + j] = p[j] * r;
    __syncthreads();
    const int base = (n * 64 + h) * 6400;
    for (int idx = tid; idx < 6400; idx += 256) ker[base + idx] = sm[idx];
}

// ---------------- content-aware reassembly + pixel shuffle ----------------
// x: (N,128,64,64), ker: (N,H,W,100), out: (N,128,128,128)
// Block = (n, h, 16-channel chunk). Thread = (w, 4-channel group) -> 4c x 4(s,t).
__global__ __launch_bounds__(256) void reassembly_k(
    const float* __restrict__ x, const float* __restrict__ ker,
    float* __restrict__ out)
{
    constexpr int CT = 16;
    __shared__ float xls[CT][5][68];   // [c][row][col], col = w+2 (replicate pad)
    __shared__ float kls[64 * 108];    // [w][q], pad 108 to spread banks
    const int blk = blockIdx.x;
    const int cb = blk & 7, h = (blk >> 3) & 63, n = blk >> 9;
    const int c0 = cb * CT;
    const int tid = threadIdx.x;
    const int w = tid & 63, cgq = tid >> 6;

    // stage x with replicate padding (rows h-2..h+2, cols -2..65)
    for (int idx = tid; idx < CT * 5 * 68; idx += 256) {
        int ci = idx / 340, r = idx % 340;
        int rr = r / 68, col = r % 68;
        int sr = min(max(h - 2 + rr, 0), 63);
        int sc = min(max(col - 2, 0), 63);
        xls[ci][rr][col] = x[((n * 128 + c0 + ci) * 64 + sr) * 64 + sc];
    }
    // stage ker row (pixel-major, coalesced read)
    {
        const int base = (n * 64 + h) * 6400;
        for (int idx = tid; idx < 6400; idx += 256) {
            int ww = idx / 100, q = idx % 100;
            kls[ww * 108 + q] = ker[base + idx];
        }
    }
    __syncthreads();

    float acc[4][4] = {};
    #pragma unroll
    for (int i = 0; i < 5; ++i) {
        #pragma unroll
        for (int j = 0; j < 5; ++j) {
            // q = ((i*5+j)*2+s)*2+t -> 4 consecutive (s,t) values
            const float4 kv = *(const float4*)&kls[w * 108 + (i * 5 + j) * 4];
            #pragma unroll
            for (int cc = 0; cc < 4; ++cc) {
                const float xv = xls[cgq * 4 + cc][i][w + j];
                acc[cc][0] = fmaf(xv, kv.x, acc[cc][0]);
                acc[cc][1] = fmaf(xv, kv.y, acc[cc][1]);
                acc[cc][2] = fmaf(xv, kv.z, acc[cc][2]);
                acc[cc][3] = fmaf(xv, kv.w, acc[cc][3]);
            }
        }
    }
    #pragma unroll
    for (int cc = 0; cc < 4; ++cc) {
        const int c = c0 + cgq * 4 + cc;
        #pragma unroll
        for (int s = 0; s < 2; ++s) {
            float2 v = make_float2(acc[cc][s * 2], acc[cc][s * 2 + 1]);
            *(float2*)&out[((n * 128 + c) * 128 + 2 * h + s) * 128 + 2 * w] = v;
        }
    }
}

extern "C" void kernel_launch(void* const* d_in, const int* in_sizes, int n_in,
                              void* d_out, int out_size, void* d_ws, size_t ws_size,
                              hipStream_t stream) {
    const float* x     = (const float*)d_in[0];
    const float* w_enc = (const float*)d_in[1];
    const float* b_enc = (const float*)d_in[2];
    const float* gamma = (const float*)d_in[3];
    const float* beta  = (const float*)d_in[4];
    const float* mean  = (const float*)d_in[5];
    const float* var   = (const float*)d_in[6];
    const float* w_kp  = (const float*)d_in[7];
    const float* b_kp  = (const float*)d_in[8];
    const float* w_g1  = (const float*)d_in[9];
    const float* b_g1  = (const float*)d_in[10];
    const float* w_g2  = (const float*)d_in[11];
    const float* b_g2  = (const float*)d_in[12];
    float* out = (float*)d_out;

    // workspace carve: content (8*64*64*64) | g1relu (same) | ker (8*64*64*100)
    float* content = (float*)d_ws;
    float* g1r     = content + 2097152;
    float* ker     = g1r + 2097152;

    conv3x3_k<128, true><<<512, 256, 0, stream>>>(
        x, w_enc, b_enc, gamma, beta, mean, var, content);
    conv3x3_k<64, false><<<512, 256, 0, stream>>>(
        content, w_g1, b_g1, nullptr, nullptr, nullptr, nullptr, g1r);
    predictor_k<<<512, 256, 0, stream>>>(content, g1r, w_kp, b_kp, w_g2, b_g2, ker);
    reassembly_k<<<4096, 256, 0, stream>>>(x, ker, out);
}

// Round 2
// 217.105 us; speedup vs baseline: 1.7685x; 1.7685x over previous
//
#include <hip/hip_runtime.h>
#include <hip/hip_bf16.h>

// CARAFE-style SAU. Round 2: both 3x3 convs as bf16 MFMA implicit GEMM.
// N=8, Cin=128, H=W=64, Cmid=64, NK=100, K=5, S=2.

typedef __attribute__((ext_vector_type(8))) short short8;
typedef __attribute__((ext_vector_type(4))) float f32x4;

// ---------------- prep: x (N,128,64,64) f32 -> xb (N,64,64,128) bf16 ----------------
__global__ __launch_bounds__(256) void x_to_bf_nhwc(const float* __restrict__ x,
                                                    __hip_bfloat16* __restrict__ xb) {
    __shared__ float ls[128 * 65];
    const int blk = blockIdx.x, n = blk >> 6, h = blk & 63;
    const int tid = threadIdx.x;
    for (int idx = tid; idx < 8192; idx += 256) {
        int ci = idx >> 6, w = idx & 63;
        ls[ci * 65 + w] = x[((n * 128 + ci) * 64 + h) * 64 + w];
    }
    __syncthreads();
    for (int idx = tid; idx < 8192; idx += 256) {
        int w = idx >> 7, ci = idx & 127;
        xb[((n * 64 + h) * 64 + w) * 128 + ci] = __float2bfloat16(ls[ci * 65 + w]);
    }
}

// ---------------- prep: weights (64,CI,3,3) f32 -> (3,3,64,CI) bf16 ----------------
__global__ void w_to_bf(const float* __restrict__ w, __hip_bfloat16* __restrict__ o,
                        int CI, int total) {
    int idx = blockIdx.x * 256 + threadIdx.x;
    if (idx >= total) return;
    int ci = idx % CI;
    int t = idx / CI;
    int co = t & 63;
    int p = t >> 6;  // kh*3+kw
    o[idx] = __float2bfloat16(w[(co * CI + ci) * 9 + p]);
}

// ---------------- conv3x3 via MFMA 16x16x32 bf16 ----------------
// xb: (N,64,64,CIN) bf16; wt: (3,3,64,CIN) bf16.
// Block per (n,h). 4 waves, wave wv -> couts [wv*16, wv*16+16). M = 64 pixels (4 m-tiles).
// Epilogue: BN+ReLU (conv1) or bias+ReLU (conv2); optional NHWC f32 / NHWC bf16 outs.
template<int CIN>
__global__ __launch_bounds__(256) void conv3x3_mfma(
    const __hip_bfloat16* __restrict__ xb, const __hip_bfloat16* __restrict__ wt,
    const float* __restrict__ bias, const float* __restrict__ gamma,
    const float* __restrict__ beta, const float* __restrict__ mean,
    const float* __restrict__ var,
    float* __restrict__ out_f32,          // (N,64,64,64) NHWC f32, may be null
    __hip_bfloat16* __restrict__ out_bf)  // (N,64,64,64) NHWC bf16, may be null
{
    constexpr int CINP = CIN + 8;  // +8 bf16 pad -> uniform LDS bank load on b128 frag reads
    __shared__ short xs[3 * 66 * CINP];
    const int blk = blockIdx.x, n = blk >> 6, h = blk & 63;
    const int tid = threadIdx.x;
    const int lane = tid & 63, wave = tid >> 6;
    const int m = lane & 15, q = lane >> 4;
    const int co0 = wave * 16;

    // stage rows h-1..h+1, cols -1..64 (zero pad), ci-contiguous, 16B chunks
    const short8 zero8 = {0, 0, 0, 0, 0, 0, 0, 0};
    for (int idx = tid; idx < 3 * 66 * (CIN / 8); idx += 256) {
        int c8 = idx % (CIN / 8);
        int p = idx / (CIN / 8);
        int r = p / 66, w = p % 66;
        int hh = h + r - 1, wc = w - 1;
        short8 v = zero8;
        if ((unsigned)hh < 64u && (unsigned)wc < 64u)
            v = *(const short8*)&xb[(((n * 64 + hh) * 64 + wc) * CIN) + c8 * 8];
        *(short8*)&xs[(r * 66 + w) * CINP + c8 * 8] = v;
    }
    __syncthreads();

    f32x4 acc[4] = {{0.f, 0.f, 0.f, 0.f}, {0.f, 0.f, 0.f, 0.f},
                    {0.f, 0.f, 0.f, 0.f}, {0.f, 0.f, 0.f, 0.f}};
    const int kbase = q * 8;
    #pragma unroll
    for (int kh = 0; kh < 3; ++kh) {
        #pragma unroll
        for (int kw = 0; kw < 3; ++kw) {
            // B frag: B[k=ci][n=co], lane holds co = co0+m, k = q*8..+8 (per ci-chunk)
            const __hip_bfloat16* wp = &wt[((kh * 3 + kw) * 64 + co0 + m) * CIN + kbase];
            // A frag: A[m=pixel][k=ci]; pixel w uses input col w+kw (xs col0 = -1)
            const short* xp = &xs[(kh * 66 + kw + m) * CINP + kbase];
            #pragma unroll
            for (int kc = 0; kc < CIN / 32; ++kc) {
                short8 bfrag = *(const short8*)&wp[kc * 32];
                #pragma unroll
                for (int mt = 0; mt < 4; ++mt) {
                    short8 afrag = *(const short8*)&xp[mt * 16 * CINP + kc * 32];
                    acc[mt] = __builtin_amdgcn_mfma_f32_16x16x32_bf16(
                        afrag, bfrag, acc[mt], 0, 0, 0);
                }
            }
        }
    }

    // epilogue: C/D layout col(lane&15)=cout, row(q*4+reg)=pixel w
    const int c = co0 + m;
    float sc, sh;
    if (gamma) {
        float inv = rsqrtf(var[c] + 1e-5f);
        sc = gamma[c] * inv;
        sh = (bias[c] - mean[c]) * sc + beta[c];
    } else {
        sc = 1.f;
        sh = bias[c];
    }
    #pragma unroll
    for (int mt = 0; mt < 4; ++mt) {
        const int w0 = mt * 16 + q * 4;
        float ov[4];
        #pragma unroll
        for (int r = 0; r < 4; ++r)
            ov[r] = fmaxf(fmaf(acc[mt][r], sc, sh), 0.f);
        if (out_f32) {
            #pragma unroll
            for (int r = 0; r < 4; ++r)
                out_f32[((n * 64 + h) * 64 + (w0 + r)) * 64 + c] = ov[r];
        }
        if (out_bf) {
            #pragma unroll
            for (int r = 0; r < 4; ++r)
                out_bf[((n * 64 + h) * 64 + (w0 + r)) * 64 + c] = __float2bfloat16(ov[r]);
        }
    }
}

// ---------------- fused kernel/gate predictor + softmax ----------------
// cb: content bf16 (N,64,64,64) NHWC; g1: f32 (N,64,64,64) NHWC.
// wkp,wg2: (100,64); out ker: (N,H,W,100) pixel-major.
__global__ __launch_bounds__(256) void predictor_k(
    const __hip_bfloat16* __restrict__ cb, const float* __restrict__ g1,
    const float* __restrict__ wkp, const float* __restrict__ bkp,
    const float* __restrict__ wg2, const float* __restrict__ bg2,
    float* __restrict__ ker)
{
    __shared__ float cs[64 * 68];    // [w][ci], pad 68
    __shared__ float gs[64 * 68];
    __shared__ float wsm[100 * 64];  // [q][ci] (staged twice: wkp then wg2)
    __shared__ float redm[256], reds[256];
    const int blk = blockIdx.x;
    const int n = blk >> 6, h = blk & 63;
    const int tid = threadIdx.x;
    const int w = tid & 63, qg = tid >> 6;

    for (int idx = tid; idx < 4096; idx += 256) {
        int ww = idx >> 6, ci = idx & 63;
        const int gidx = ((n * 64 + h) * 64 + ww) * 64 + ci;
        cs[ww * 68 + ci] = __bfloat162float(cb[gidx]);
        gs[ww * 68 + ci] = g1[gidx];
    }
    for (int idx = tid; idx < 6400; idx += 256) wsm[idx] = wkp[idx];
    __syncthreads();

    float ka[25], ga[25];
    #pragma unroll
    for (int j = 0; j < 25; ++j) ka[j] = bkp[qg * 25 + j];
    for (int ci = 0; ci < 64; ci += 4) {
        const float4 cv = *(const float4*)&cs[w * 68 + ci];
        #pragma unroll
        for (int j = 0; j < 25; ++j) {
            const float4 wv = *(const float4*)&wsm[(qg * 25 + j) * 64 + ci];
            ka[j] = fmaf(cv.x, wv.x, ka[j]);
            ka[j] = fmaf(cv.y, wv.y, ka[j]);
            ka[j] = fmaf(cv.z, wv.z, ka[j]);
            ka[j] = fmaf(cv.w, wv.w, ka[j]);
        }
    }
    __syncthreads();
    for (int idx = tid; idx < 6400; idx += 256) wsm[idx] = wg2[idx];
    __syncthreads();
    #pragma unroll
    for (int j = 0; j < 25; ++j) ga[j] = bg2[qg * 25 + j];
    for (int ci = 0; ci < 64; ci += 4) {
        const float4 gv = *(const float4*)&gs[w * 68 + ci];
        #pragma unroll
        for (int j = 0; j < 25; ++j) {
            const float4 wv = *(const float4*)&wsm[(qg * 25 + j) * 64 + ci];
            ga[j] = fmaf(gv.x, wv.x, ga[j]);
            ga[j] = fmaf(gv.y, wv.y, ga[j]);
            ga[j] = fmaf(gv.z, wv.z, ga[j]);
            ga[j] = fmaf(gv.w, wv.w, ga[j]);
        }
    }

    float p[25], m = -1e30f;
    #pragma unroll
    for (int j = 0; j < 25; ++j) {
        float s = 1.f / (1.f + __expf(-ga[j]));
        p[j] = ka[j] * s;
        m = fmaxf(m, p[j]);
    }
    redm[tid] = m;
    __syncthreads();
    m = fmaxf(fmaxf(redm[w], redm[64 + w]), fmaxf(redm[128 + w], redm[192 + w]));
    float ssum = 0.f;
    #pragma unroll
    for (int j = 0; j < 25; ++j) { p[j] = __expf(p[j] - m); ssum += p[j]; }
    reds[tid] = ssum;
    __syncthreads();
    ssum = reds[w] + reds[64 + w] + reds[128 + w] + reds[192 + w];
    const float r = 1.f / ssum;

    float* sm = cs;  // reuse cs+gs region (contiguous, 8704 floats >= 6400)
    #pragma unroll
    for (int j = 0; j < 25; ++j) sm[w * 100 + qg * 25 + j] = p[j] * r;
    __syncthreads();
    const int base = (n * 64 + h) * 6400;
    for (int idx = tid; idx < 6400; idx += 256) ker[base + idx] = sm[idx];
}

// ---------------- content-aware reassembly + pixel shuffle ----------------
__global__ __launch_bounds__(256) void reassembly_k(
    const float* __restrict__ x, const float* __restrict__ ker,
    float* __restrict__ out)
{
    constexpr int CT = 16;
    __shared__ float xls[CT][5][68];
    __shared__ float kls[64 * 108];
    const int blk = blockIdx.x;
    const int cb = blk & 7, h = (blk >> 3) & 63, n = blk >> 9;
    const int c0 = cb * CT;
    const int tid = threadIdx.x;
    const int w = tid & 63, cgq = tid >> 6;

    for (int idx = tid; idx < CT * 5 * 68; idx += 256) {
        int ci = idx / 340, r = idx % 340;
        int rr = r / 68, col = r % 68;
        int sr = min(max(h - 2 + rr, 0), 63);
        int sc = min(max(col - 2, 0), 63);
        xls[ci][rr][col] = x[((n * 128 + c0 + ci) * 64 + sr) * 64 + sc];
    }
    {
        const int base = (n * 64 + h) * 6400;
        for (int idx = tid; idx < 6400; idx += 256) {
            int ww = idx / 100, q = idx % 100;
            kls[ww * 108 + q] = ker[base + idx];
        }
    }
    __syncthreads();

    float acc[4][4] = {};
    #pragma unroll
    for (int i = 0; i < 5; ++i) {
        #pragma unroll
        for (int j = 0; j < 5; ++j) {
            const float4 kv = *(const float4*)&kls[w * 108 + (i * 5 + j) * 4];
            #pragma unroll
            for (int cc = 0; cc < 4; ++cc) {
                const float xv = xls[cgq * 4 + cc][i][w + j];
                acc[cc][0] = fmaf(xv, kv.x, acc[cc][0]);
                acc[cc][1] = fmaf(xv, kv.y, acc[cc][1]);
                acc[cc][2] = fmaf(xv, kv.z, acc[cc][2]);
                acc[cc][3] = fmaf(xv, kv.w, acc[cc][3]);
            }
        }
    }
    #pragma unroll
    for (int cc = 0; cc < 4; ++cc) {
        const int c = c0 + cgq * 4 + cc;
        #pragma unroll
        for (int s = 0; s < 2; ++s) {
            float2 v = make_float2(acc[cc][s * 2], acc[cc][s * 2 + 1]);
            *(float2*)&out[((n * 128 + c) * 128 + 2 * h + s) * 128 + 2 * w] = v;
        }
    }
}

extern "C" void kernel_launch(void* const* d_in, const int* in_sizes, int n_in,
                              void* d_out, int out_size, void* d_ws, size_t ws_size,
                              hipStream_t stream) {
    const float* x     = (const float*)d_in[0];
    const float* w_enc = (const float*)d_in[1];
    const float* b_enc = (const float*)d_in[2];
    const float* gamma = (const float*)d_in[3];
    const float* beta  = (const float*)d_in[4];
    const float* mean  = (const float*)d_in[5];
    const float* var   = (const float*)d_in[6];
    const float* w_kp  = (const float*)d_in[7];
    const float* b_kp  = (const float*)d_in[8];
    const float* w_g1  = (const float*)d_in[9];
    const float* b_g1  = (const float*)d_in[10];
    const float* w_g2  = (const float*)d_in[11];
    const float* b_g2  = (const float*)d_in[12];
    float* out = (float*)d_out;

    // workspace carve
    float* g1r = (float*)d_ws;                     // (N,64,64,64) NHWC f32
    float* ker = g1r + 2097152;                    // (N,H,W,100)  f32
    __hip_bfloat16* xb  = (__hip_bfloat16*)(ker + 3276800);  // (N,64,64,128) bf16
    __hip_bfloat16* cbf = xb + 4194304;            // content (N,64,64,64) bf16
    __hip_bfloat16* wtt = cbf + 2097152;           // (3,3,64,128) bf16
    __hip_bfloat16* wgt = wtt + 73728;             // (3,3,64,64) bf16

    x_to_bf_nhwc<<<512, 256, 0, stream>>>(x, xb);
    w_to_bf<<<288, 256, 0, stream>>>(w_enc, wtt, 128, 73728);
    w_to_bf<<<144, 256, 0, stream>>>(w_g1, wgt, 64, 36864);

    conv3x3_mfma<128><<<512, 256, 0, stream>>>(
        xb, wtt, b_enc, gamma, beta, mean, var, nullptr, cbf);
    conv3x3_mfma<64><<<512, 256, 0, stream>>>(
        cbf, wgt, b_g1, nullptr, nullptr, nullptr, nullptr, g1r, nullptr);

    predictor_k<<<512, 256, 0, stream>>>(cbf, g1r, w_kp, b_kp, w_g2, b_g2, ker);
    reassembly_k<<<4096, 256, 0, stream>>>(x, ker, out);
}